// Round 18
// baseline (105.342 us; speedup 1.0000x reference)
//
#include <hip/hip_runtime.h>
#include <hip/hip_bf16.h>
#include <math.h>

// ---- problem constants ----
#define B_ROWS 512
#define D_K    512
#define C_CLS  100000

#define COS_M 0.8775825618903728f
#define SIN_M 0.479425538604203f
#define TH_C  (-0.8775825618903728f)    // cos(pi - m)
#define MM_C  0.2397127693021015f       // sin(pi - m) * m

#define LOG2E_S 92.33248261689366f      // 64 * log2(e)
#define M0      92.4f                   // fixed softmax bound: |cos|<=1 -> |L|<=92.33
#define LN2F    0.6931471805599453f

#define BN 64                           // classes per chunk
#define NCHUNK 1563                     // ceil(100000/64)
#define NSTRIP 256                      // col-strips

typedef __attribute__((ext_vector_type(4))) float f32x4;
typedef __attribute__((ext_vector_type(4))) int   i32x4;
typedef __attribute__((ext_vector_type(2))) long long i64x2;

__device__ inline float fexp2(float x) {
#if __has_builtin(__builtin_amdgcn_exp2f)
    return __builtin_amdgcn_exp2f(x);
#else
    return exp2f(x);
#endif
}
#define VMCNT0() asm volatile("s_waitcnt vmcnt(0)" ::: "memory")
#define LGKM0()  asm volatile("s_waitcnt lgkmcnt(0)" ::: "memory")
#define RAWBAR() __builtin_amdgcn_s_barrier()
#define SCHED0() __builtin_amdgcn_sched_barrier(0)

// ---------------- kernel 0: row-normalize -> fp8 e4m3, kk-INTERLEAVED layout ------
// (x only). Per-row byte permutation: pos = ks*64 + hi*16 + kk*8 + inner for
// original k-byte = ks*64 + kk*32 + hi*8 + inner.
__global__ __launch_bounds__(256) void rownorm8p_kernel(const float* __restrict__ in,
                                                        uint2* __restrict__ out,
                                                        float* __restrict__ rnout,
                                                        int nvalid) {
    const int wid = threadIdx.x >> 6;
    const int lane = threadIdx.x & 63;
    const int r = blockIdx.x * 4 + wid;
    const int newg = ((lane >> 3) << 3) + ((lane & 3) << 1) + ((lane >> 2) & 1);
    if (r >= nvalid) {
        out[(size_t)r * 64 + newg] = make_uint2(0u, 0u);
        return;
    }
    const float* row = in + (size_t)r * D_K + lane * 8;
    float4 a = *(const float4*)row;
    float4 b = *(const float4*)(row + 4);
    float ss = a.x * a.x + a.y * a.y + a.z * a.z + a.w * a.w
             + b.x * b.x + b.y * b.y + b.z * b.z + b.w * b.w;
    ss += __shfl_xor(ss, 1);  ss += __shfl_xor(ss, 2);  ss += __shfl_xor(ss, 4);
    ss += __shfl_xor(ss, 8);  ss += __shfl_xor(ss, 16); ss += __shfl_xor(ss, 32);
    const float rn = 1.0f / sqrtf(ss);
    int u0 = __builtin_amdgcn_cvt_pk_fp8_f32(a.x * rn, a.y * rn, 0, false);
    u0     = __builtin_amdgcn_cvt_pk_fp8_f32(a.z * rn, a.w * rn, u0, true);
    int u1 = __builtin_amdgcn_cvt_pk_fp8_f32(b.x * rn, b.y * rn, 0, false);
    u1     = __builtin_amdgcn_cvt_pk_fp8_f32(b.z * rn, b.w * rn, u1, true);
    out[(size_t)r * 64 + newg] = make_uint2((unsigned)u0, (unsigned)u1);
    if (rnout != nullptr && lane == 0) rnout[r] = rn;
}

// ---------------- kernel 1: single-pass fused strip GEMM (r15 skeleton) ----------
// Reads raw fp32 W once; stager quantizes -> kk-interleaved swizzled fp8 into a
// 4x16KB LDS ring, 2 half-chunks ahead; ss=sum(v^2) folded; 1/|w| applied
// post-dot inside exp2 (rnsh, double-buffered). Barriers: lgkmcnt(0)-only per
// half-chunk (fp32 loads never drained). A fp8 via volatile-asm loads (128 VGPR).
__global__ __launch_bounds__(256) void gemm_fused5_kernel(
        const unsigned char* __restrict__ xnb8p,  // [512][512] fp8 norm, interleaved
        const float* __restrict__ w,              // [100000][512] fp32 raw
        float* __restrict__ partials) {           // [512][NSTRIP] row-major
    const int t    = threadIdx.x;
    const int lane = t & 63;
    const int wid  = t >> 6;
    const int cl   = lane & 15;
    const int hi   = lane >> 4;
    const int swz  = (cl >> 1) & 3;

    // XCD-pair mapping: rb-twins (same strip) share an XCD -> W L2-shared.
    const int j   = blockIdx.x;
    const int s   = (j & 7) * 32 + ((j >> 3) >> 1);   // col-strip 0..255
    const int rb  = (j >> 3) & 1;                     // rowblock
    const int ch0 = (s * NCHUNK) >> 8;
    const int ch1 = ((s + 1) * NCHUNK) >> 8;
    const int nch = ch1 - ch0;
    const int cbase = ch0 * BN;

    __shared__ char  smem[4 * 16384];                 // fp8 ring
    __shared__ float rnsh[2][64];

    // stager identity: thread covers row srow, kslice q (of each half), 64 bytes.
    const int srow = t >> 2;
    const int q    = t & 3;
    const int sw   = (srow >> 1) & 3;                 // 16B-granule swizzle

    f32x4 pA0, pA1, pA2, pA3;                         // stage set A (16 floats)
    f32x4 pB0, pB1, pB2, pB3;                         // stage set B
    float ssv = 0.f;

    // ISSUE2: load pair gp (16 floats = source bytes [gp*16,gp*16+16)) of half Hs
#define ISSUE2(Hs, gp, S)                                                        \
    {                                                                            \
        int _c = cbase + ((Hs) >> 1) * 64 + srow;                                \
        _c = _c < C_CLS ? _c : C_CLS - 1;                                        \
        const float* _p = w + (size_t)_c * 512 +                                 \
                          (((Hs) & 1) * 4 + q) * 64 + (gp) * 16;                 \
        p##S##0 = *(const f32x4*)_p;       p##S##1 = *(const f32x4*)(_p + 4);    \
        p##S##2 = *(const f32x4*)(_p + 8); p##S##3 = *(const f32x4*)(_p + 12);   \
    }
    // CONV2: quantize pair gp -> two b64 writes in kk-interleaved+swizzled layout
#define CONV2(Hs, gp, S)                                                         \
    {                                                                            \
        f32x4 _a = p##S##0, _b = p##S##1, _c2 = p##S##2, _d = p##S##3;           \
        ssv += _a[0]*_a[0] + _a[1]*_a[1] + _a[2]*_a[2] + _a[3]*_a[3]             \
             + _b[0]*_b[0] + _b[1]*_b[1] + _b[2]*_b[2] + _b[3]*_b[3]             \
             + _c2[0]*_c2[0] + _c2[1]*_c2[1] + _c2[2]*_c2[2] + _c2[3]*_c2[3]     \
             + _d[0]*_d[0] + _d[1]*_d[1] + _d[2]*_d[2] + _d[3]*_d[3];            \
        int _u0 = __builtin_amdgcn_cvt_pk_fp8_f32(_a[0], _a[1], 0, false);       \
        _u0     = __builtin_amdgcn_cvt_pk_fp8_f32(_a[2], _a[3], _u0, true);      \
        int _u1 = __builtin_amdgcn_cvt_pk_fp8_f32(_b[0], _b[1], 0, false);       \
        _u1     = __builtin_amdgcn_cvt_pk_fp8_f32(_b[2], _b[3], _u1, true);      \
        int _u2 = __builtin_amdgcn_cvt_pk_fp8_f32(_c2[0], _c2[1], 0, false);     \
        _u2     = __builtin_amdgcn_cvt_pk_fp8_f32(_c2[2], _c2[3], _u2, true);    \
        int _u3 = __builtin_amdgcn_cvt_pk_fp8_f32(_d[0], _d[1], 0, false);       \
        _u3     = __builtin_amdgcn_cvt_pk_fp8_f32(_d[2], _d[3], _u3, true);      \
        char* _dst = smem + ((Hs) & 3) * 16384 + q * 4096 + srow * 64;           \
        const int _kk = (gp) >> 1;                                               \
        *(uint2*)(_dst + ((((2 * (gp)) & 3) ^ sw) << 4) + _kk * 8) =             \
            make_uint2((unsigned)_u0, (unsigned)_u1);                            \
        *(uint2*)(_dst + ((((2 * (gp) + 1) & 3) ^ sw) << 4) + _kk * 8) =         \
            make_uint2((unsigned)_u2, (unsigned)_u3);                            \
    }

    // ---- A: 64 rows/wave, full K, volatile-asm loads (un-rematerializable) ----
    i32x4 a8v[4][8];
#pragma unroll
    for (int m = 0; m < 4; ++m) {
        const unsigned char* ap =
            xnb8p + (size_t)(rb * 256 + wid * 64 + m * 16 + cl) * 512 + hi * 16;
#pragma unroll
        for (int k = 0; k < 8; ++k) {
            unsigned long long addr = (unsigned long long)(ap + k * 64);
            asm volatile("global_load_dwordx4 %0, %1, off"
                         : "=v"(a8v[m][k]) : "v"(addr));
        }
    }
    VMCNT0();

    // ---- prologue: stage chunk 0 (halves 0,1) pipelined; rnsh[0] ----
    ISSUE2(0, 0, A)
    ISSUE2(0, 1, B)
    CONV2(0, 0, A) ISSUE2(0, 2, A)
    CONV2(0, 1, B) ISSUE2(0, 3, B)
    CONV2(0, 2, A) ISSUE2(1, 0, A)
    CONV2(0, 3, B) ISSUE2(1, 1, B)
    CONV2(1, 0, A) ISSUE2(1, 2, A)
    CONV2(1, 1, B) ISSUE2(1, 3, B)
    CONV2(1, 2, A)
    CONV2(1, 3, B)
    {
        float a = ssv;
        a += __shfl_xor(a, 1);
        a += __shfl_xor(a, 2);
        if (q == 0) {
            const int c = cbase + srow;
            rnsh[0][srow] = (c < C_CLS) ? (1.0f / sqrtf(a)) : 0.0f;
        }
        ssv = 0.f;
    }
    __syncthreads();

    float sums[16];
#pragma unroll
    for (int i = 0; i < 16; ++i) sums[i] = 0.f;

#define COMPUTE_K(bufbyte, AIDX, k)                                              \
    {                                                                            \
        const char* sB = smem + (bufbyte);                                       \
        i64x2 bfr[4];                                                            \
        _Pragma("unroll")                                                        \
        for (int n = 0; n < 4; ++n)                                              \
            bfr[n] = *(const i64x2*)(sB + (k) * 4096 + (n * 16 + cl) * 64 +      \
                                     ((hi ^ swz) << 4));                         \
        _Pragma("unroll")                                                        \
        for (int m = 0; m < 4; ++m) {                                            \
            const i64x2 av = __builtin_bit_cast(i64x2, a8v[m][AIDX]);            \
            _Pragma("unroll")                                                    \
            for (int n = 0; n < 4; ++n)                                          \
                acc[m][n] = __builtin_amdgcn_mfma_f32_16x16x32_fp8_fp8(          \
                    av[0], bfr[n][0], acc[m][n], 0, 0, 0);                       \
            _Pragma("unroll")                                                    \
            for (int n = 0; n < 4; ++n)                                          \
                acc[m][n] = __builtin_amdgcn_mfma_f32_16x16x32_fp8_fp8(          \
                    av[1], bfr[n][1], acc[m][n], 0, 0, 0);                       \
        }                                                                        \
    }

    for (int ci = 0; ci < nch; ++ci) {
        const bool stg = (ci + 1) < nch;
        const int Hs0 = 2 * ci + 2;               // stages chunk ci+1 half 0
        const int Hs1 = 2 * ci + 3;               // stages chunk ci+1 half 1
        const int b0 = ((2 * ci) & 3) * 16384;    // compute buffer, half 0
        const int b1 = ((2 * ci + 1) & 3) * 16384;

        f32x4 acc[4][4];
#pragma unroll
        for (int m = 0; m < 4; ++m)
#pragma unroll
            for (int n = 0; n < 4; ++n) acc[m][n] = (f32x4){0.f, 0.f, 0.f, 0.f};

        // ---- half 0 ----
        if (stg) ISSUE2(Hs0, 0, A)
        COMPUTE_K(b0, 0, 0)
        if (stg) { CONV2(Hs0, 0, A) ISSUE2(Hs0, 1, B) }
        COMPUTE_K(b0, 1, 1)
        if (stg) { CONV2(Hs0, 1, B) ISSUE2(Hs0, 2, A) }
        COMPUTE_K(b0, 2, 2)
        if (stg) { CONV2(Hs0, 2, A) ISSUE2(Hs0, 3, B) }
        COMPUTE_K(b0, 3, 3)
        if (stg) CONV2(Hs0, 3, B)
        LGKM0();
        SCHED0();
        RAWBAR();

        // ---- half 1 ----
        if (stg) ISSUE2(Hs1, 0, A)
        COMPUTE_K(b1, 4, 0)
        if (stg) { CONV2(Hs1, 0, A) ISSUE2(Hs1, 1, B) }
        COMPUTE_K(b1, 5, 1)
        if (stg) { CONV2(Hs1, 1, B) ISSUE2(Hs1, 2, A) }
        COMPUTE_K(b1, 6, 2)
        if (stg) { CONV2(Hs1, 2, A) ISSUE2(Hs1, 3, B) }
        COMPUTE_K(b1, 7, 3)
        if (stg) CONV2(Hs1, 3, B)

        // chunk ci+1's ss complete -> rnsh[(ci+1)&1]
        if (stg) {
            float a = ssv;
            a += __shfl_xor(a, 1);
            a += __shfl_xor(a, 2);
            if (q == 0) {
                const int c = cbase + (ci + 1) * 64 + srow;
                rnsh[(ci + 1) & 1][srow] = (c < C_CLS) ? (1.0f / sqrtf(a)) : 0.0f;
            }
            ssv = 0.f;
        }

        // fixed-M0 accumulation with post-dot row norm (pad rows: rn=0 -> 2^-92.4)
        {
            float rl[4];
#pragma unroll
            for (int n = 0; n < 4; ++n) rl[n] = rnsh[ci & 1][n * 16 + cl] * LOG2E_S;
#pragma unroll
            for (int m = 0; m < 4; ++m)
#pragma unroll
                for (int jj = 0; jj < 4; ++jj)
#pragma unroll
                    for (int n = 0; n < 4; ++n)
                        sums[m * 4 + jj] += fexp2(fmaf(acc[m][n][jj], rl[n], -M0));
        }
        LGKM0();
        SCHED0();
        RAWBAR();
    }
#undef ISSUE2
#undef CONV2
#undef COMPUTE_K

    // ---- strip epilogue: reduce tracked rows across 16 col-lanes ----
#pragma unroll
    for (int m = 0; m < 4; ++m)
#pragma unroll
        for (int jj = 0; jj < 4; ++jj) {
            float v = sums[m * 4 + jj];
            v += __shfl_xor(v, 1);
            v += __shfl_xor(v, 2);
            v += __shfl_xor(v, 4);
            v += __shfl_xor(v, 8);
            if (cl == 0) {
                const int r = rb * 256 + wid * 64 + m * 16 + hi * 4 + jj;
                partials[(size_t)r * NSTRIP + s] = v;
            }
        }
}

// ---------------- kernel 2: target-class cosine (fp32 exact) ----------------
__global__ __launch_bounds__(256) void tdot_kernel(const float* __restrict__ x,
                                                   const float* __restrict__ w,
                                                   const int* __restrict__ tgt,
                                                   const float* __restrict__ xrn,
                                                   float* __restrict__ tdot) {
    const int wid = threadIdx.x >> 6;
    const int lane = threadIdx.x & 63;
    const int b = blockIdx.x * 4 + wid;
    const int tg = tgt[b];
    const float* xr = x + (size_t)b * D_K + lane * 8;
    const float* wr = w + (size_t)tg * D_K + lane * 8;
    float4 xa = *(const float4*)xr;
    float4 xb = *(const float4*)(xr + 4);
    float4 wa = *(const float4*)wr;
    float4 wb = *(const float4*)(wr + 4);
    float xw = xa.x * wa.x + xa.y * wa.y + xa.z * wa.z + xa.w * wa.w
             + xb.x * wb.x + xb.y * wb.y + xb.z * wb.z + xb.w * wb.w;
    float ww = wa.x * wa.x + wa.y * wa.y + wa.z * wa.z + wa.w * wa.w
             + wb.x * wb.x + wb.y * wb.y + wb.z * wb.z + wb.w * wb.w;
#pragma unroll
    for (int m = 1; m < 64; m <<= 1) {
        xw += __shfl_xor(xw, m);
        ww += __shfl_xor(ww, m);
    }
    if (lane == 0) tdot[b] = xw * xrn[b] / sqrtf(ww);
}

// ---------------- kernel 3a: per-row loss (margin fixup) ----------------
__global__ __launch_bounds__(256) void rowloss_kernel(const float* __restrict__ partials,
                                                      const float* __restrict__ tdot,
                                                      float* __restrict__ rowloss) {
    const int wid = threadIdx.x >> 6;
    const int lane = threadIdx.x & 63;
    const int r = blockIdx.x * 4 + wid;
    const float* pr = partials + (size_t)r * NSTRIP;
    float s2 = pr[lane] + pr[lane + 64] + pr[lane + 128] + pr[lane + 192];
    s2 += __shfl_xor(s2, 1);  s2 += __shfl_xor(s2, 2);  s2 += __shfl_xor(s2, 4);
    s2 += __shfl_xor(s2, 8);  s2 += __shfl_xor(s2, 16); s2 += __shfl_xor(s2, 32);
    if (lane == 0) {
        const float cst = tdot[r];
        float c2 = 1.0f - cst * cst;
        c2 = fminf(fmaxf(c2, 0.0f), 1.0f);
        const float sine = sqrtf(c2);
        float phi = cst * COS_M - sine * SIN_M;
        phi = (cst > TH_C) ? phi : (cst - MM_C);
        const float Lt = cst * LOG2E_S;
        const float Lp = phi * LOG2E_S;
        s2 = s2 - fexp2(Lt - M0) + fexp2(Lp - M0);
        rowloss[r] = LN2F * (M0 + log2f(s2) - Lp);
    }
}

// ---------------- kernel 3b: mean ----------------
__global__ __launch_bounds__(512) void mean_kernel(const float* __restrict__ rowloss,
                                                   float* __restrict__ out) {
    const int b = threadIdx.x;
    float v = rowloss[b];
    v += __shfl_xor(v, 1);  v += __shfl_xor(v, 2);  v += __shfl_xor(v, 4);
    v += __shfl_xor(v, 8);  v += __shfl_xor(v, 16); v += __shfl_xor(v, 32);
    __shared__ float sW[8];
    if ((b & 63) == 0) sW[b >> 6] = v;
    __syncthreads();
    if (b == 0) {
        float tot = 0.f;
#pragma unroll
        for (int wv = 0; wv < 8; ++wv) tot += sW[wv];
        out[0] = tot * (1.0f / (float)B_ROWS);
    }
}

extern "C" void kernel_launch(void* const* d_in, const int* in_sizes, int n_in,
                              void* d_out, int out_size, void* d_ws, size_t ws_size,
                              hipStream_t stream) {
    const float* x = (const float*)d_in[0];
    const float* w = (const float*)d_in[1];
    const int* tgt = (const int*)d_in[2];
    float* out = (float*)d_out;

    char* ws = (char*)d_ws;
    size_t off = 0;
    unsigned char* xnb8 = (unsigned char*)(ws + off);
    off += (size_t)B_ROWS * D_K;                       // 256 KB
    off = (off + 255) & ~(size_t)255;
    float* xrn = (float*)(ws + off);
    off += B_ROWS * 4;
    off = (off + 255) & ~(size_t)255;
    float* partials = (float*)(ws + off);
    off += (size_t)B_ROWS * NSTRIP * 4;                // 512 KB
    off = (off + 255) & ~(size_t)255;
    float* tdot = (float*)(ws + off);
    off += B_ROWS * 4;
    off = (off + 255) & ~(size_t)255;
    float* rowloss = (float*)(ws + off);
    off += B_ROWS * 4;

    rownorm8p_kernel<<<B_ROWS / 4, 256, 0, stream>>>(x, (uint2*)xnb8, xrn, B_ROWS);
    tdot_kernel<<<B_ROWS / 4, 256, 0, stream>>>(x, w, tgt, xrn, tdot);
    gemm_fused5_kernel<<<NSTRIP * 2, 256, 0, stream>>>(xnb8, w, partials);
    rowloss_kernel<<<B_ROWS / 4, 256, 0, stream>>>(partials, tdot, rowloss);
    mean_kernel<<<1, 512, 0, stream>>>(rowloss, out);
}

// Round 20
// 98.210 us; speedup vs baseline: 1.0726x; 1.0726x over previous
//
#include <hip/hip_runtime.h>
#include <hip/hip_bf16.h>
#include <math.h>

// ---- problem constants ----
#define B_ROWS 512
#define D_K    512
#define C_CLS  100000
#define C_PAD  100032                   // NCHUNK*64 (pad rows = fp8 zeros)

#define COS_M 0.8775825618903728f
#define SIN_M 0.479425538604203f
#define TH_C  (-0.8775825618903728f)    // cos(pi - m)
#define MM_C  0.2397127693021015f       // sin(pi - m) * m

#define LOG2E_S 92.33248261689366f      // 64 * log2(e)
#define M0      92.4f                   // fixed softmax bound: |cos|<=1 -> |L|<=92.33
#define LN2F    0.6931471805599453f

#define BN 64                           // classes per chunk
#define NCHUNK 1563                     // ceil(100000/64)
#define NSTRIP 256                      // col-strips

typedef __attribute__((ext_vector_type(4))) float f32x4;
typedef __attribute__((ext_vector_type(2))) long long i64x2;
typedef long long i64;

__device__ inline float fexp2(float x) {
#if __has_builtin(__builtin_amdgcn_exp2f)
    return __builtin_amdgcn_exp2f(x);
#else
    return exp2f(x);
#endif
}
__device__ inline void gload16(const void* g, void* lds) {
    __builtin_amdgcn_global_load_lds(
        (const __attribute__((address_space(1))) unsigned int*)g,
        (__attribute__((address_space(3))) unsigned int*)lds, 16, 0, 0);
}
#define VMCNT8() asm volatile("s_waitcnt vmcnt(8)" ::: "memory")
#define RAWBAR() __builtin_amdgcn_s_barrier()
#define SCHED0() __builtin_amdgcn_sched_barrier(0)

// ---------------- kernel 0: row-normalize -> fp8 e4m3, kk-INTERLEAVED layout ------
// Permuted per-row byte order: pos = ks*64 + hi*16 + kk*8 + inner for original
// k-byte = ks*64 + kk*32 + hi*8 + inner.  A 16B read at row*512 + ks*64 + hi*16
// yields the (kk0,kk1) MFMA fragment pair for lane-group hi, contiguous.
__global__ __launch_bounds__(256) void rownorm8p_kernel(const float* __restrict__ in,
                                                        uint2* __restrict__ out,
                                                        float* __restrict__ rnout,
                                                        int nvalid) {
    const int wid = threadIdx.x >> 6;
    const int lane = threadIdx.x & 63;
    const int r = blockIdx.x * 4 + wid;
    const int newg = ((lane >> 3) << 3) + ((lane & 3) << 1) + ((lane >> 2) & 1);
    if (r >= nvalid) {
        out[(size_t)r * 64 + newg] = make_uint2(0u, 0u);
        return;
    }
    const float* row = in + (size_t)r * D_K + lane * 8;
    float4 a = *(const float4*)row;
    float4 b = *(const float4*)(row + 4);
    float ss = a.x * a.x + a.y * a.y + a.z * a.z + a.w * a.w
             + b.x * b.x + b.y * b.y + b.z * b.z + b.w * b.w;
    ss += __shfl_xor(ss, 1);  ss += __shfl_xor(ss, 2);  ss += __shfl_xor(ss, 4);
    ss += __shfl_xor(ss, 8);  ss += __shfl_xor(ss, 16); ss += __shfl_xor(ss, 32);
    const float rn = 1.0f / sqrtf(ss);
    int u0 = __builtin_amdgcn_cvt_pk_fp8_f32(a.x * rn, a.y * rn, 0, false);
    u0     = __builtin_amdgcn_cvt_pk_fp8_f32(a.z * rn, a.w * rn, u0, true);
    int u1 = __builtin_amdgcn_cvt_pk_fp8_f32(b.x * rn, b.y * rn, 0, false);
    u1     = __builtin_amdgcn_cvt_pk_fp8_f32(b.z * rn, b.w * rn, u1, true);
    out[(size_t)r * 64 + newg] = make_uint2((unsigned)u0, (unsigned)u1);
    if (rnout != nullptr && lane == 0) rnout[r] = rn;
}

// ---------------- kernel 1: fp8 strip GEMM, half-chunk ring-4, counted vmcnt -----
// 256 thr / 4 waves; wave owns 64 rows; A fp8 pinned in regs (a8[4][16]).
// Staging: half-chunk = 64 classes x 256 K = 16 KB, ring of 4 LDS buffers.
// Each half-iteration: issue stage(h+2) [4 gload_lds], wait vmcnt(8) (h's loads
// landed; h+1/h+2 stay in flight -- NEVER drained to 0), s_barrier, compute
// 4 ksteps.  Statically specialized per k-half (no runtime a8 indices).
// XCD-pair swizzle: both rowblocks of a strip share an XCD -> wn8p L2-shared.
__global__ __launch_bounds__(256, 2) void gemm_ring_kernel(
        const unsigned char* __restrict__ xnb8p,  // [512][512] fp8 norm, interleaved
        const unsigned char* __restrict__ wn8p,   // [C_PAD][512] fp8 norm, interleaved
        float* __restrict__ partials) {           // [NSTRIP][512]
    const int t    = threadIdx.x;
    const int lane = t & 63;
    const int wid  = t >> 6;
    const int cl   = lane & 15;
    const int hi   = lane >> 4;
    const int swz  = (cl >> 1) & 3;

    // XCD-pair mapping (512 blocks): xcd = j&7; pair index p = j>>3.
    const int j   = blockIdx.x;
    const int s   = (j & 7) * 32 + ((j >> 3) >> 1);   // col-strip 0..255
    const int rb  = (j >> 3) & 1;                     // rowblock
    const int ch0 = (s * NCHUNK) >> 8;
    const int ch1 = ((s + 1) * NCHUNK) >> 8;
    const int nch = ch1 - ch0;
    const int cbase = ch0 * BN;
    const int H   = nch * 2;                          // half-chunks

    __shared__ char smem[4 * 16384];                  // 64 KB ring

    // staging identity: thread t covers row t>>2 of each kslice, granule lane&3;
    // source granule pre-swizzled (involution, matches read-side ^swz).
    const int srow = t >> 2;
    const int sgl  = (lane & 3) ^ ((lane >> 3) & 3);

#define STAGEH(hsrc, bufi)                                                      \
    {                                                                           \
        const int _ci = (hsrc) >> 1, _kh = (hsrc) & 1;                          \
        const unsigned char* _b = wn8p +                                        \
            (size_t)(cbase + _ci * 64 + srow) * 512 + _kh * 256 + (sgl << 4);   \
        char* _d = smem + (bufi) * 16384 + wid * 1024;                          \
        _Pragma("unroll")                                                       \
        for (int _j = 0; _j < 4; ++_j)                                          \
            gload16(_b + _j * 64, _d + _j * 4096);                              \
    }

    // ---- A: 64 rows/wave, full K, fp8 pinned in regs (direct global loads) ----
    i64 a8[4][16];
#pragma unroll
    for (int m = 0; m < 4; ++m) {
        const unsigned char* ap =
            xnb8p + (size_t)(rb * 256 + wid * 64 + m * 16 + cl) * 512 + hi * 16;
#pragma unroll
        for (int k = 0; k < 8; ++k) {
            i64x2 q = *(const i64x2*)(ap + k * 64);
            a8[m][k * 2]     = q[0];
            a8[m][k * 2 + 1] = q[1];
        }
    }
#pragma unroll
    for (int m = 0; m < 4; ++m)
#pragma unroll
        for (int i = 0; i < 16; ++i)
            asm volatile("" : "+v"(a8[m][i]));   // forces vmcnt wait + pins A

    // ---- prologue: stage half-chunks 0,1 (8 loads outstanding) ----
    STAGEH(0, 0)
    STAGEH(1, 1)

    float sums[16];
#pragma unroll
    for (int i = 0; i < 16; ++i) sums[i] = 0.f;

    // COMPUTE_HALF: 4 ksteps from LDS buffer, KH is a compile-time k-half (0/1)
#define COMPUTE_HALF(bufbyte, KH)                                               \
    {                                                                           \
        const char* sB = smem + (bufbyte);                                      \
        _Pragma("unroll")                                                       \
        for (int k = 0; k < 4; ++k) {                                           \
            i64x2 bfr[4];                                                       \
            _Pragma("unroll")                                                   \
            for (int n = 0; n < 4; ++n)                                         \
                bfr[n] = *(const i64x2*)(sB + k * 4096 + (n * 16 + cl) * 64 +   \
                                         ((hi ^ swz) << 4));                    \
            _Pragma("unroll")                                                   \
            for (int m = 0; m < 4; ++m)                                         \
                _Pragma("unroll")                                               \
                for (int n = 0; n < 4; ++n)                                     \
                    acc[m][n] = __builtin_amdgcn_mfma_f32_16x16x32_fp8_fp8(     \
                        a8[m][((KH) * 4 + k) * 2], bfr[n][0], acc[m][n],        \
                        0, 0, 0);                                               \
            _Pragma("unroll")                                                   \
            for (int m = 0; m < 4; ++m)                                         \
                _Pragma("unroll")                                               \
                for (int n = 0; n < 4; ++n)                                     \
                    acc[m][n] = __builtin_amdgcn_mfma_f32_16x16x32_fp8_fp8(     \
                        a8[m][((KH) * 4 + k) * 2 + 1], bfr[n][1], acc[m][n],    \
                        0, 0, 0);                                               \
        }                                                                       \
    }

    for (int ci = 0; ci < nch; ++ci) {
        const int sbase = (ci & 1) << 1;        // buffers being computed: sbase, sbase+1
        const int dbase = sbase ^ 2;            // buffers being staged: dbase, dbase+1
        const int h0 = 2 * ci, h1 = h0 + 1;

        f32x4 acc[4][4];
#pragma unroll
        for (int m = 0; m < 4; ++m)
#pragma unroll
            for (int n = 0; n < 4; ++n) acc[m][n] = (f32x4){0.f, 0.f, 0.f, 0.f};

        // ---- half 0 ----
        {
            const int hs = (h0 + 2 < H) ? h0 + 2 : H - 1;   // dummy re-stage at tail
            STAGEH(hs, dbase)
        }
        SCHED0();
        VMCNT8();      // h0's 4 loads landed; h1/h0+2 remain in flight
        RAWBAR();
        COMPUTE_HALF(sbase * 16384, 0)

        // ---- half 1 ----
        {
            const int hs = (h1 + 2 < H) ? h1 + 2 : H - 1;
            STAGEH(hs, dbase + 1)
        }
        SCHED0();
        VMCNT8();
        RAWBAR();
        COMPUTE_HALF((sbase + 1) * 16384, 1)

        // ---- chunk epilogue: fixed-M0 accumulation (pad rows -> 2^-92.4 ~ 0) ----
#pragma unroll
        for (int m = 0; m < 4; ++m)
#pragma unroll
            for (int jj = 0; jj < 4; ++jj)
#pragma unroll
                for (int n = 0; n < 4; ++n)
                    sums[m * 4 + jj] += fexp2(fmaf(acc[m][n][jj], LOG2E_S, -M0));
    }
#undef STAGEH
#undef COMPUTE_HALF

    // ---- strip epilogue: reduce each tracked row across its 16 col-lanes ----
#pragma unroll
    for (int m = 0; m < 4; ++m)
#pragma unroll
        for (int jj = 0; jj < 4; ++jj) {
            float v = sums[m * 4 + jj];
            v += __shfl_xor(v, 1);
            v += __shfl_xor(v, 2);
            v += __shfl_xor(v, 4);
            v += __shfl_xor(v, 8);
            if (cl == 0) {
                const int r = rb * 256 + wid * 64 + m * 16 + hi * 4 + jj;
                partials[s * B_ROWS + r] = v;
            }
        }
}

// ---------------- kernel 2: target-class cosine (fp32 exact) ----------------
__global__ __launch_bounds__(256) void tdot_kernel(const float* __restrict__ x,
                                                   const float* __restrict__ w,
                                                   const int* __restrict__ tgt,
                                                   const float* __restrict__ xrn,
                                                   float* __restrict__ tdot) {
    const int wid = threadIdx.x >> 6;
    const int lane = threadIdx.x & 63;
    const int b = blockIdx.x * 4 + wid;
    const int tg = tgt[b];
    const float* xr = x + (size_t)b * D_K + lane * 8;
    const float* wr = w + (size_t)tg * D_K + lane * 8;
    float4 xa = *(const float4*)xr;
    float4 xb = *(const float4*)(xr + 4);
    float4 wa = *(const float4*)wr;
    float4 wb = *(const float4*)(wr + 4);
    float xw = xa.x * wa.x + xa.y * wa.y + xa.z * wa.z + xa.w * wa.w
             + xb.x * wb.x + xb.y * wb.y + xb.z * wb.z + xb.w * wb.w;
    float ww = wa.x * wa.x + wa.y * wa.y + wa.z * wa.z + wa.w * wa.w
             + wb.x * wb.x + wb.y * wb.y + wb.z * wb.z + wb.w * wb.w;
#pragma unroll
    for (int m = 1; m < 64; m <<= 1) {
        xw += __shfl_xor(xw, m);
        ww += __shfl_xor(ww, m);
    }
    if (lane == 0) tdot[b] = xw * xrn[b] / sqrtf(ww);
}

// ---------------- kernel 3: per-row loss (margin fixup) + mean ----------------
__global__ __launch_bounds__(512) void final_kernel(const float* __restrict__ partials,
                                                    const float* __restrict__ tdot,
                                                    float* __restrict__ out) {
    const int b = threadIdx.x;   // 512 threads = 8 waves
    float s2 = 0.f;
    for (int s = 0; s < NSTRIP; ++s) s2 += partials[s * B_ROWS + b];
    const float cst = tdot[b];
    float c2 = 1.0f - cst * cst;
    c2 = fminf(fmaxf(c2, 0.0f), 1.0f);
    const float sine = sqrtf(c2);
    float phi = cst * COS_M - sine * SIN_M;
    phi = (cst > TH_C) ? phi : (cst - MM_C);
    const float Lt = cst * LOG2E_S;
    const float Lp = phi * LOG2E_S;
    // swap plain-target term for margin term in the denominator
    s2 = s2 - fexp2(Lt - M0) + fexp2(Lp - M0);
    float loss = LN2F * (M0 + log2f(s2) - Lp);
    loss += __shfl_xor(loss, 1);  loss += __shfl_xor(loss, 2);
    loss += __shfl_xor(loss, 4);  loss += __shfl_xor(loss, 8);
    loss += __shfl_xor(loss, 16); loss += __shfl_xor(loss, 32);
    __shared__ float sW[8];
    if ((b & 63) == 0) sW[b >> 6] = loss;
    __syncthreads();
    if (b == 0) {
        float tot = 0.f;
#pragma unroll
        for (int wv = 0; wv < 8; ++wv) tot += sW[wv];
        out[0] = tot * (1.0f / (float)B_ROWS);
    }
}

extern "C" void kernel_launch(void* const* d_in, const int* in_sizes, int n_in,
                              void* d_out, int out_size, void* d_ws, size_t ws_size,
                              hipStream_t stream) {
    const float* x = (const float*)d_in[0];
    const float* w = (const float*)d_in[1];
    const int* tgt = (const int*)d_in[2];
    float* out = (float*)d_out;

    char* ws = (char*)d_ws;
    size_t off = 0;
    unsigned char* xnb8 = (unsigned char*)(ws + off);
    off += (size_t)B_ROWS * D_K;                       // 256 KB
    off = (off + 255) & ~(size_t)255;
    unsigned char* wn8 = (unsigned char*)(ws + off);
    off += (size_t)C_PAD * D_K;                        // 51.2 MB
    off = (off + 255) & ~(size_t)255;
    float* xrn = (float*)(ws + off);
    off += B_ROWS * 4;
    off = (off + 255) & ~(size_t)255;
    float* partials = (float*)(ws + off);
    off += (size_t)NSTRIP * B_ROWS * 4;                // 512 KB
    off = (off + 255) & ~(size_t)255;
    float* tdot = (float*)(ws + off);
    off += B_ROWS * 4;

    rownorm8p_kernel<<<B_ROWS / 4, 256, 0, stream>>>(x, (uint2*)xnb8, xrn, B_ROWS);
    rownorm8p_kernel<<<C_PAD / 4, 256, 0, stream>>>(w, (uint2*)wn8, nullptr, C_CLS);
    tdot_kernel<<<B_ROWS / 4, 256, 0, stream>>>(x, w, tgt, xrn, tdot);
    gemm_ring_kernel<<<NSTRIP * 2, 256, 0, stream>>>(xnb8, wn8, partials);
    final_kernel<<<1, 512, 0, stream>>>(partials, tdot, out);
}